// Round 1
// baseline (1045.429 us; speedup 1.0000x reference)
//
#include <hip/hip_runtime.h>

typedef unsigned short u16;
typedef __attribute__((ext_vector_type(8))) short bf16x8;
typedef __attribute__((ext_vector_type(8))) unsigned short u16x8;
typedef __attribute__((ext_vector_type(4))) float f32x4;

__device__ __forceinline__ u16 f2bf(float f) {
  union { float f; unsigned u; } v; v.f = f;
  unsigned r = v.u + 0x7fffu + ((v.u >> 16) & 1u);
  return (u16)(r >> 16);
}

__device__ __forceinline__ void gload16(const u16* g, u16* l) {
  __builtin_amdgcn_global_load_lds((const __attribute__((address_space(1))) void*)g,
                                   (__attribute__((address_space(3))) void*)l, 16, 0, 0);
}

// ---------------- cast f32 -> bf16 (contiguous) ----------------
__global__ __launch_bounds__(256) void cast_bf16_kern(const float* __restrict__ in,
                                                      u16* __restrict__ out, int n) {
  int i = (blockIdx.x * 256 + threadIdx.x) * 8;
  if (i >= n) return;
  float4 a = *(const float4*)(in + i);
  float4 b = *(const float4*)(in + i + 4);
  u16x8 r;
  r[0] = f2bf(a.x); r[1] = f2bf(a.y); r[2] = f2bf(a.z); r[3] = f2bf(a.w);
  r[4] = f2bf(b.x); r[5] = f2bf(b.y); r[6] = f2bf(b.z); r[7] = f2bf(b.w);
  *(u16x8*)(out + i) = r;
}

// ---------------- transpose + cast: in[K][N] f32 -> out[N][K] bf16 ----------------
__global__ __launch_bounds__(256) void transpose_cast_kern(const float* __restrict__ in,
                                                           u16* __restrict__ out, int K, int N) {
  __shared__ float tile[32][33];
  int nbx = N >> 5;
  int n0 = (blockIdx.x % nbx) << 5;
  int k0 = (blockIdx.x / nbx) << 5;
  int tx = threadIdx.x & 31, ty = threadIdx.x >> 5;
#pragma unroll
  for (int i = 0; i < 4; i++)
    tile[ty + i * 8][tx] = in[(size_t)(k0 + ty + i * 8) * N + n0 + tx];
  __syncthreads();
#pragma unroll
  for (int i = 0; i < 4; i++)
    out[(size_t)(n0 + ty + i * 8) * K + k0 + tx] = f2bf(tile[tx][ty + i * 8]);
}

// ---------------- GEMM: C[M,N] = A[M,K] * Bt[N,K]^T, bf16 in, MFMA 16x16x32 ----------------
// MODE 0: bf16 row-major C.  MODE 1: bf16 write transposed V layout [B][Hkv][D][S].
// MODE 2: f32 row-major C.
template <int MODE>
__global__ __launch_bounds__(256) void gemm_bt(const u16* __restrict__ A,
                                               const u16* __restrict__ Bt,
                                               void* __restrict__ Cout,
                                               int M, int N, int K) {
  __shared__ u16 As[128 * 32];
  __shared__ u16 Bs[128 * 32];
  const int tid = threadIdx.x;
  const int lane = tid & 63, wv = tid >> 6;
  const int wr = wv >> 1, wc = wv & 1;
  const int li = lane & 15, lg = lane >> 4;
  const int nbx = N >> 7;
  const int m0 = (blockIdx.x / nbx) << 7;
  const int n0 = (blockIdx.x % nbx) << 7;

  f32x4 acc[4][4];
#pragma unroll
  for (int m = 0; m < 4; m++)
#pragma unroll
    for (int n = 0; n < 4; n++) acc[m][n] = (f32x4){0.f, 0.f, 0.f, 0.f};

  // staging geometry: pass p (0/1), wave wv stages 1KB at tile rows (p*4+wv)*16..+15
  const int srow = wv * 16 + (lane >> 2);
  const int skoff = (lane & 3) * 8;
  const u16* ag0 = A + (size_t)(m0 + srow) * K + skoff;
  const u16* ag1 = A + (size_t)(m0 + srow + 64) * K + skoff;
  const u16* bg0 = Bt + (size_t)(n0 + srow) * K + skoff;
  const u16* bg1 = Bt + (size_t)(n0 + srow + 64) * K + skoff;
  u16* al = As + wv * 512;
  u16* bl = Bs + wv * 512;

  for (int kt = 0; kt < K; kt += 32) {
    __syncthreads();
    gload16(ag0 + kt, al);
    gload16(ag1 + kt, al + 2048);
    gload16(bg0 + kt, bl);
    gload16(bg1 + kt, bl + 2048);
    __syncthreads();
    bf16x8 af[4], bfr[4];
#pragma unroll
    for (int m = 0; m < 4; m++)
      af[m] = *(const bf16x8*)(As + (wr * 64 + m * 16 + li) * 32 + lg * 8);
#pragma unroll
    for (int n = 0; n < 4; n++)
      bfr[n] = *(const bf16x8*)(Bs + (wc * 64 + n * 16 + li) * 32 + lg * 8);
#pragma unroll
    for (int m = 0; m < 4; m++)
#pragma unroll
      for (int n = 0; n < 4; n++)
        acc[m][n] = __builtin_amdgcn_mfma_f32_16x16x32_bf16(af[m], bfr[n], acc[m][n], 0, 0, 0);
  }

#pragma unroll
  for (int m = 0; m < 4; m++)
#pragma unroll
    for (int n = 0; n < 4; n++)
#pragma unroll
      for (int r = 0; r < 4; r++) {
        int gm = m0 + wr * 64 + m * 16 + lg * 4 + r;
        int gn = n0 + wc * 64 + n * 16 + li;
        float val = acc[m][n][r];
        if (MODE == 0) {
          ((u16*)Cout)[(size_t)gm * N + gn] = f2bf(val);
        } else if (MODE == 2) {
          ((float*)Cout)[(size_t)gm * N + gn] = val;
        } else {  // V^T: [B][Hkv][D][S]
          int b = gm >> 11, s = gm & 2047, kvh = gn >> 7, d = gn & 127;
          ((u16*)Cout)[(size_t)((b * 8 + kvh) * 128 + d) * 2048 + s] = f2bf(val);
        }
      }
}

// ---------------- flash attention: GQA causal, QBLK=64 (4 waves x 16 rows), KVBLK=64 ----------------
__global__ __launch_bounds__(256) void flash_attn_kern(const u16* __restrict__ Q,
                                                       const u16* __restrict__ Kg,
                                                       const u16* __restrict__ VT,
                                                       u16* __restrict__ Og) {
  int bid = blockIdx.x;
  int qt = bid & 31;
  int h = (bid >> 5) & 31;
  int b = bid >> 10;
  int kvh = h >> 2;
  const int tid = threadIdx.x;
  const int lane = tid & 63, w = tid >> 6;
  const int li = lane & 15, lg = lane >> 4;
  const int q0 = qt << 6;

  __shared__ u16 Ks[64 * 136];   // [64][128+8] pad keeps 16B align, shifts banks
  __shared__ u16 Vs[128 * 72];   // V^T tile [128 d][64+8 kv]
  __shared__ u16 Ps[4][16 * 72]; // per-wave P tile [16 q][64+8 kv]

  bf16x8 qf[4];
  {
    const u16* qp = Q + (size_t)(b * 2048 + q0 + w * 16 + li) * 4096 + h * 128 + lg * 8;
#pragma unroll
    for (int ks = 0; ks < 4; ks++) qf[ks] = *(const bf16x8*)(qp + ks * 32);
  }
  f32x4 oa[8];
#pragma unroll
  for (int n = 0; n < 8; n++) oa[n] = (f32x4){0.f, 0.f, 0.f, 0.f};
  float m_run[4], l_run[4];
#pragma unroll
  for (int r = 0; r < 4; r++) { m_run[r] = -1e30f; l_run[r] = 0.f; }

  const float scale = 0.08838834764831845f;  // 1/sqrt(128)
  const int ntiles = (q0 >> 6) + 1;

  for (int t = 0; t < ntiles; t++) {
    const int kv0 = t << 6;
    __syncthreads();
    // stage K tile [64][128] -> Ks (coalesced 16B chunks)
#pragma unroll
    for (int j = 0; j < 4; j++) {
      int chunk = j * 256 + tid;
      int r = chunk >> 4;
      int ce = (chunk & 15) * 8;
      *(bf16x8*)(Ks + r * 136 + ce) =
          *(const bf16x8*)(Kg + (size_t)(b * 2048 + kv0 + r) * 1024 + kvh * 128 + ce);
    }
    // stage V^T tile [128][64] -> Vs
#pragma unroll
    for (int j = 0; j < 4; j++) {
      int chunk = j * 256 + tid;
      int d = chunk >> 3;
      int ce = (chunk & 7) * 8;
      *(bf16x8*)(Vs + d * 72 + ce) =
          *(const bf16x8*)(VT + (size_t)((b * 8 + kvh) * 128 + d) * 2048 + kv0 + ce);
    }
    __syncthreads();

    // S = Q K^T  (per wave: 16 q rows x 64 kv cols)
    f32x4 sacc[4];
#pragma unroll
    for (int n = 0; n < 4; n++) sacc[n] = (f32x4){0.f, 0.f, 0.f, 0.f};
#pragma unroll
    for (int n = 0; n < 4; n++)
#pragma unroll
      for (int ks = 0; ks < 4; ks++) {
        bf16x8 kf = *(const bf16x8*)(Ks + (n * 16 + li) * 136 + ks * 32 + lg * 8);
        sacc[n] = __builtin_amdgcn_mfma_f32_16x16x32_bf16(qf[ks], kf, sacc[n], 0, 0, 0);
      }

    float p[4][4];
#pragma unroll
    for (int n = 0; n < 4; n++) {
      int kvg = kv0 + n * 16 + li;
#pragma unroll
      for (int r = 0; r < 4; r++) {
        int qg = q0 + w * 16 + lg * 4 + r;
        float v = sacc[n][r] * scale;
        p[n][r] = (kvg > qg) ? -1e30f : v;
      }
    }

    // online softmax, rows spread over 16-lane groups
#pragma unroll
    for (int r = 0; r < 4; r++) {
      float mx = fmaxf(fmaxf(p[0][r], p[1][r]), fmaxf(p[2][r], p[3][r]));
#pragma unroll
      for (int dm = 1; dm < 16; dm <<= 1) mx = fmaxf(mx, __shfl_xor(mx, dm, 64));
      float mnew = fmaxf(m_run[r], mx);
      float corr = __expf(m_run[r] - mnew);
      m_run[r] = mnew;
      float ls = 0.f;
#pragma unroll
      for (int n = 0; n < 4; n++) { p[n][r] = __expf(p[n][r] - mnew); ls += p[n][r]; }
#pragma unroll
      for (int dm = 1; dm < 16; dm <<= 1) ls += __shfl_xor(ls, dm, 64);
      l_run[r] = l_run[r] * corr + ls;
#pragma unroll
      for (int n = 0; n < 8; n++) oa[n][r] *= corr;
    }

    // P -> LDS (re-fragment for PV A-operand)
    u16* pw = Ps[w];
#pragma unroll
    for (int n = 0; n < 4; n++)
#pragma unroll
      for (int r = 0; r < 4; r++)
        pw[(lg * 4 + r) * 72 + n * 16 + li] = f2bf(p[n][r]);
    asm volatile("s_waitcnt lgkmcnt(0)" ::: "memory");

    // O += P V
#pragma unroll
    for (int ks = 0; ks < 2; ks++) {
      bf16x8 pf = *(const bf16x8*)(pw + li * 72 + ks * 32 + lg * 8);
#pragma unroll
      for (int n = 0; n < 8; n++) {
        bf16x8 vf = *(const bf16x8*)(Vs + (n * 16 + li) * 72 + ks * 32 + lg * 8);
        oa[n] = __builtin_amdgcn_mfma_f32_16x16x32_bf16(pf, vf, oa[n], 0, 0, 0);
      }
    }
  }

  float inv[4];
#pragma unroll
  for (int r = 0; r < 4; r++) inv[r] = 1.f / l_run[r];
#pragma unroll
  for (int n = 0; n < 8; n++)
#pragma unroll
    for (int r = 0; r < 4; r++)
      Og[(size_t)(b * 2048 + q0 + w * 16 + lg * 4 + r) * 4096 + h * 128 + n * 16 + li] =
          f2bf(oa[n][r] * inv[r]);
}

extern "C" void kernel_launch(void* const* d_in, const int* in_sizes, int n_in,
                              void* d_out, int out_size, void* d_ws, size_t ws_size,
                              hipStream_t stream) {
  (void)in_sizes; (void)n_in; (void)out_size; (void)ws_size;
  const float* hs = (const float*)d_in[0];
  const float* wq = (const float*)d_in[1];
  const float* wk = (const float*)d_in[2];
  const float* wv = (const float*)d_in[3];
  const float* wo = (const float*)d_in[4];

  u16* ws   = (u16*)d_ws;
  u16* hs_b = ws;               // [4096][4096]
  u16* wqT  = hs_b + 16777216;  // [4096][4096]
  u16* wkT  = wqT + 16777216;   // [1024][4096]
  u16* wvT  = wkT + 4194304;    // [1024][4096]
  u16* woT  = wvT + 4194304;    // [4096][4096]
  u16* Qb   = woT + 16777216;   // [4096][4096]
  u16* Kb   = Qb + 16777216;    // [4096][1024]
  u16* VTb  = Kb + 4194304;     // [2][8][128][2048]
  u16* attnb = VTb + 4194304;   // [4096][4096]
  // total 201,326,592 bytes of d_ws

  cast_bf16_kern<<<8192, 256, 0, stream>>>(hs, hs_b, 16777216);
  transpose_cast_kern<<<16384, 256, 0, stream>>>(wq, wqT, 4096, 4096);
  transpose_cast_kern<<<4096, 256, 0, stream>>>(wk, wkT, 4096, 1024);
  transpose_cast_kern<<<4096, 256, 0, stream>>>(wv, wvT, 4096, 1024);
  transpose_cast_kern<<<16384, 256, 0, stream>>>(wo, woT, 4096, 4096);

  gemm_bt<0><<<1024, 256, 0, stream>>>(hs_b, wqT, Qb, 4096, 4096, 4096);
  gemm_bt<0><<<256, 256, 0, stream>>>(hs_b, wkT, Kb, 4096, 1024, 4096);
  gemm_bt<1><<<256, 256, 0, stream>>>(hs_b, wvT, VTb, 4096, 1024, 4096);

  flash_attn_kern<<<2048, 256, 0, stream>>>(Qb, Kb, VTb, attnb);

  gemm_bt<2><<<1024, 256, 0, stream>>>(attnb, woT, (float*)d_out, 4096, 4096, 4096);
}

// Round 2
// 740.993 us; speedup vs baseline: 1.4108x; 1.4108x over previous
//
#include <hip/hip_runtime.h>

typedef unsigned short u16;
typedef __attribute__((ext_vector_type(8))) short bf16x8;
typedef __attribute__((ext_vector_type(8))) unsigned short u16x8;
typedef __attribute__((ext_vector_type(4))) float f32x4;

__device__ __forceinline__ u16 f2bf(float f) {
  union { float f; unsigned u; } v; v.f = f;
  unsigned r = v.u + 0x7fffu + ((v.u >> 16) & 1u);
  return (u16)(r >> 16);
}

__device__ __forceinline__ void gload16(const u16* g, u16* l) {
  __builtin_amdgcn_global_load_lds((const __attribute__((address_space(1))) void*)g,
                                   (__attribute__((address_space(3))) void*)l, 16, 0, 0);
}

// ---------------- cast f32 -> bf16 (contiguous) ----------------
__global__ __launch_bounds__(256) void cast_bf16_kern(const float* __restrict__ in,
                                                      u16* __restrict__ out, int n) {
  int i = (blockIdx.x * 256 + threadIdx.x) * 8;
  if (i >= n) return;
  float4 a = *(const float4*)(in + i);
  float4 b = *(const float4*)(in + i + 4);
  u16x8 r;
  r[0] = f2bf(a.x); r[1] = f2bf(a.y); r[2] = f2bf(a.z); r[3] = f2bf(a.w);
  r[4] = f2bf(b.x); r[5] = f2bf(b.y); r[6] = f2bf(b.z); r[7] = f2bf(b.w);
  *(u16x8*)(out + i) = r;
}

// ---------------- transpose + cast: in[K][N] f32 -> out[N][K] bf16 ----------------
__global__ __launch_bounds__(256) void transpose_cast_kern(const float* __restrict__ in,
                                                           u16* __restrict__ out, int K, int N) {
  __shared__ float tile[32][33];
  int nbx = N >> 5;
  int n0 = (blockIdx.x % nbx) << 5;
  int k0 = (blockIdx.x / nbx) << 5;
  int tx = threadIdx.x & 31, ty = threadIdx.x >> 5;
#pragma unroll
  for (int i = 0; i < 4; i++)
    tile[ty + i * 8][tx] = in[(size_t)(k0 + ty + i * 8) * N + n0 + tx];
  __syncthreads();
#pragma unroll
  for (int i = 0; i < 4; i++)
    out[(size_t)(n0 + ty + i * 8) * K + k0 + tx] = f2bf(tile[tx][ty + i * 8]);
}

// ---------------- GEMM: C[M,N] = A[M,K] * Bt[N,K]^T, bf16 in, MFMA 16x16x32 ----------------
template <int MODE>
__global__ __launch_bounds__(256) void gemm_bt(const u16* __restrict__ A,
                                               const u16* __restrict__ Bt,
                                               void* __restrict__ Cout,
                                               int M, int N, int K) {
  __shared__ u16 As[128 * 32];
  __shared__ u16 Bs[128 * 32];
  const int tid = threadIdx.x;
  const int lane = tid & 63, wv = tid >> 6;
  const int wr = wv >> 1, wc = wv & 1;
  const int li = lane & 15, lg = lane >> 4;
  const int nbx = N >> 7;
  const int m0 = (blockIdx.x / nbx) << 7;
  const int n0 = (blockIdx.x % nbx) << 7;

  f32x4 acc[4][4];
#pragma unroll
  for (int m = 0; m < 4; m++)
#pragma unroll
    for (int n = 0; n < 4; n++) acc[m][n] = (f32x4){0.f, 0.f, 0.f, 0.f};

  const int srow = wv * 16 + (lane >> 2);
  const int skoff = (lane & 3) * 8;
  const u16* ag0 = A + (size_t)(m0 + srow) * K + skoff;
  const u16* ag1 = A + (size_t)(m0 + srow + 64) * K + skoff;
  const u16* bg0 = Bt + (size_t)(n0 + srow) * K + skoff;
  const u16* bg1 = Bt + (size_t)(n0 + srow + 64) * K + skoff;
  u16* al = As + wv * 512;
  u16* bl = Bs + wv * 512;

  for (int kt = 0; kt < K; kt += 32) {
    __syncthreads();
    gload16(ag0 + kt, al);
    gload16(ag1 + kt, al + 2048);
    gload16(bg0 + kt, bl);
    gload16(bg1 + kt, bl + 2048);
    __syncthreads();
    bf16x8 af[4], bfr[4];
#pragma unroll
    for (int m = 0; m < 4; m++)
      af[m] = *(const bf16x8*)(As + (wr * 64 + m * 16 + li) * 32 + lg * 8);
#pragma unroll
    for (int n = 0; n < 4; n++)
      bfr[n] = *(const bf16x8*)(Bs + (wc * 64 + n * 16 + li) * 32 + lg * 8);
#pragma unroll
    for (int m = 0; m < 4; m++)
#pragma unroll
      for (int n = 0; n < 4; n++)
        acc[m][n] = __builtin_amdgcn_mfma_f32_16x16x32_bf16(af[m], bfr[n], acc[m][n], 0, 0, 0);
  }

#pragma unroll
  for (int m = 0; m < 4; m++)
#pragma unroll
    for (int n = 0; n < 4; n++)
#pragma unroll
      for (int r = 0; r < 4; r++) {
        int gm = m0 + wr * 64 + m * 16 + lg * 4 + r;
        int gn = n0 + wc * 64 + n * 16 + li;
        float val = acc[m][n][r];
        if (MODE == 0) {
          ((u16*)Cout)[(size_t)gm * N + gn] = f2bf(val);
        } else if (MODE == 2) {
          ((float*)Cout)[(size_t)gm * N + gn] = val;
        } else {  // V^T: [B][Hkv][D][S]
          int b = gm >> 11, s = gm & 2047, kvh = gn >> 7, d = gn & 127;
          ((u16*)Cout)[(size_t)((b * 8 + kvh) * 128 + d) * 2048 + s] = f2bf(val);
        }
      }
}

// ---------------- flash attention v2: GQA, block=(b,kvh,qtile32), 4 waves = 4 heads ----------------
// K/V staged once per block (shared by 4 heads), double-buffered via global_load_lds with
// both-sides XOR swizzle; 2-phase pipeline (stage next -> compute -> vmcnt(0)+barrier).
__global__ __launch_bounds__(256, 2) void flash_attn_kern(const u16* __restrict__ Qg,
                                                          const u16* __restrict__ Kg,
                                                          const u16* __restrict__ VT,
                                                          u16* __restrict__ Og) {
  const int bid = blockIdx.x;
  const int qt = 63 - (bid >> 4);  // largest-first for makespan
  const int gh = bid & 15;
  const int b = gh >> 3, kvh = gh & 7;
  const int tid = threadIdx.x;
  const int lane = tid & 63, w = tid >> 6;
  const int li = lane & 15, lg = lane >> 4;
  const int h = kvh * 4 + w;
  const int q0 = qt << 5;
  const int nt = (qt >> 1) + 1;

  __shared__ u16 Kbuf[2][8192];  // [64 kv][128 d], 256B rows, XOR-swizzled
  __shared__ u16 Vbuf[2][8192];  // [128 d][64 kv], 128B rows, XOR-swizzled
  __shared__ u16 Ps[4][16 * 72]; // per-wave P re-fragment buffer, padded stride

  // Q fragments: 32 rows x 128 d per wave (head h)
  bf16x8 qf[2][4];
  {
    const u16* qp = Qg + ((size_t)(b * 2048 + q0 + li)) * 4096 + h * 128 + lg * 8;
#pragma unroll
    for (int m = 0; m < 2; m++)
#pragma unroll
      for (int ks = 0; ks < 4; ks++)
        qf[m][ks] = *(const bf16x8*)(qp + (size_t)(m * 16) * 4096 + ks * 32);
  }

  // per-lane staging sources with inverse swizzle applied to the GLOBAL address
  const u16* ksrc[4];
  const u16* vsrc[4];
#pragma unroll
  for (int i = 0; i < 4; i++) {
    int c = w * 4 + i;
    int krow = c * 4 + (lane >> 4);
    int kinner = ((lane & 15) * 16) ^ ((krow & 7) << 4);  // bytes within 256B row
    ksrc[i] = Kg + (size_t)(b * 2048 + krow) * 1024 + kvh * 128 + (kinner >> 1);
    int vrow = c * 8 + (lane >> 3);
    int vinner = ((lane & 7) * 16) ^ ((vrow & 7) << 4);   // bytes within 128B row
    vsrc[i] = VT + (size_t)((b * 8 + kvh) * 128 + vrow) * 2048 + (vinner >> 1);
  }
  // prologue: stage tile 0 into buf 0
#pragma unroll
  for (int i = 0; i < 4; i++) {
    int c = w * 4 + i;
    gload16(ksrc[i], &Kbuf[0][c * 512]);
    gload16(vsrc[i], &Vbuf[0][c * 512]);
    ksrc[i] += 64 * 1024;  // next kv tile: +64 K-rows
    vsrc[i] += 64;         // next kv tile: +64 cols of V^T
  }

  f32x4 oa[2][8];
#pragma unroll
  for (int m = 0; m < 2; m++)
#pragma unroll
    for (int n = 0; n < 8; n++) oa[m][n] = (f32x4){0.f, 0.f, 0.f, 0.f};
  f32x4 lacc[2];
  lacc[0] = (f32x4){0.f, 0.f, 0.f, 0.f};
  lacc[1] = (f32x4){0.f, 0.f, 0.f, 0.f};
  float mrun[2][4];
#pragma unroll
  for (int m = 0; m < 2; m++)
#pragma unroll
    for (int r = 0; r < 4; r++) mrun[m][r] = -1e30f;

  const float scale = 0.08838834764831845f;  // 1/sqrt(128)
  bf16x8 onesf;
#pragma unroll
  for (int j = 0; j < 8; j++) onesf[j] = (short)0x3F80;  // bf16 1.0

  asm volatile("s_waitcnt vmcnt(0)\n\ts_barrier" ::: "memory");

  for (int t = 0; t < nt; ++t) {
    const int cur = t & 1;
    const u16* KB = Kbuf[cur];
    const u16* VB = Vbuf[cur];
    if (t + 1 < nt) {
#pragma unroll
      for (int i = 0; i < 4; i++) {
        int c = w * 4 + i;
        gload16(ksrc[i], &Kbuf[cur ^ 1][c * 512]);
        gload16(vsrc[i], &Vbuf[cur ^ 1][c * 512]);
        ksrc[i] += 64 * 1024;
        vsrc[i] += 64;
      }
    }

    // ---- S = Q K^T (2 m-blocks x 4 n-blocks, K=128) ----
    f32x4 sacc[2][4];
#pragma unroll
    for (int m = 0; m < 2; m++)
#pragma unroll
      for (int n = 0; n < 4; n++) sacc[m][n] = (f32x4){0.f, 0.f, 0.f, 0.f};
    __builtin_amdgcn_s_setprio(1);
#pragma unroll
    for (int n = 0; n < 4; n++) {
      int krow = n * 16 + li;
      const u16* kb = KB + krow * 128;
      int sw = (krow & 7) << 4;
#pragma unroll
      for (int ks = 0; ks < 4; ks++) {
        bf16x8 kf = *(const bf16x8*)(kb + (((ks * 64 + lg * 16) ^ sw) >> 1));
        sacc[0][n] = __builtin_amdgcn_mfma_f32_16x16x32_bf16(qf[0][ks], kf, sacc[0][n], 0, 0, 0);
        sacc[1][n] = __builtin_amdgcn_mfma_f32_16x16x32_bf16(qf[1][ks], kf, sacc[1][n], 0, 0, 0);
      }
    }
    __builtin_amdgcn_s_setprio(0);

    // ---- scale + (diagonal-tile-only) mask, in place ----
#pragma unroll
    for (int m = 0; m < 2; m++)
#pragma unroll
      for (int n = 0; n < 4; n++)
#pragma unroll
        for (int r = 0; r < 4; r++) sacc[m][n][r] *= scale;
    if (t == nt - 1) {
      const int kv0 = t * 64;
#pragma unroll
      for (int m = 0; m < 2; m++)
#pragma unroll
        for (int r = 0; r < 4; r++) {
          int q = q0 + m * 16 + lg * 4 + r;
#pragma unroll
          for (int n = 0; n < 4; n++)
            if (kv0 + n * 16 + li > q) sacc[m][n][r] = -1e30f;
        }
    }

    // ---- online softmax (max via 16-lane shuffle; sum deferred to ones-MFMA) ----
#pragma unroll
    for (int m = 0; m < 2; m++)
#pragma unroll
      for (int r = 0; r < 4; r++) {
        float mx = fmaxf(fmaxf(sacc[m][0][r], sacc[m][1][r]), fmaxf(sacc[m][2][r], sacc[m][3][r]));
        mx = fmaxf(mx, __shfl_xor(mx, 1, 64));
        mx = fmaxf(mx, __shfl_xor(mx, 2, 64));
        mx = fmaxf(mx, __shfl_xor(mx, 4, 64));
        mx = fmaxf(mx, __shfl_xor(mx, 8, 64));
        float mnew = fmaxf(mrun[m][r], mx);
        float corr = __expf(mrun[m][r] - mnew);
        mrun[m][r] = mnew;
#pragma unroll
        for (int n = 0; n < 4; n++) sacc[m][n][r] = __expf(sacc[m][n][r] - mnew);
        lacc[m][r] *= corr;
#pragma unroll
        for (int n = 0; n < 8; n++) oa[m][n][r] *= corr;
      }

    // ---- P -> per-wave LDS, re-read as A-fragments (per m, buffer reused) ----
    bf16x8 pf[2][2];
    u16* Pw = Ps[w];
#pragma unroll
    for (int m = 0; m < 2; m++) {
#pragma unroll
      for (int n = 0; n < 4; n++)
#pragma unroll
        for (int r = 0; r < 4; r++)
          Pw[(lg * 4 + r) * 72 + n * 16 + li] = f2bf(sacc[m][n][r]);
      asm volatile("s_waitcnt lgkmcnt(0)" ::: "memory");
#pragma unroll
      for (int kvs = 0; kvs < 2; kvs++)
        pf[m][kvs] = *(const bf16x8*)(Pw + li * 72 + kvs * 32 + lg * 8);
      asm volatile("s_waitcnt lgkmcnt(0)" ::: "memory");
      __builtin_amdgcn_sched_barrier(0);
    }

    // ---- O += P V ; l += P . 1 (ones-MFMA row-sum) ----
    __builtin_amdgcn_s_setprio(1);
#pragma unroll
    for (int kvs = 0; kvs < 2; kvs++) {
#pragma unroll
      for (int n = 0; n < 8; n++) {
        int vrow = n * 16 + li;
        bf16x8 vf = *(const bf16x8*)(VB + vrow * 64 +
                                     (((kvs * 64 + lg * 16) ^ ((vrow & 7) << 4)) >> 1));
        oa[0][n] = __builtin_amdgcn_mfma_f32_16x16x32_bf16(pf[0][kvs], vf, oa[0][n], 0, 0, 0);
        oa[1][n] = __builtin_amdgcn_mfma_f32_16x16x32_bf16(pf[1][kvs], vf, oa[1][n], 0, 0, 0);
      }
      lacc[0] = __builtin_amdgcn_mfma_f32_16x16x32_bf16(pf[0][kvs], onesf, lacc[0], 0, 0, 0);
      lacc[1] = __builtin_amdgcn_mfma_f32_16x16x32_bf16(pf[1][kvs], onesf, lacc[1], 0, 0, 0);
    }
    __builtin_amdgcn_s_setprio(0);

    asm volatile("s_waitcnt vmcnt(0)\n\ts_barrier" ::: "memory");
  }

  // ---- epilogue: normalize + store ----
#pragma unroll
  for (int m = 0; m < 2; m++) {
    float inv[4];
#pragma unroll
    for (int r = 0; r < 4; r++) inv[r] = 1.0f / lacc[m][r];
    u16* op = Og + (size_t)(b * 2048 + q0 + m * 16 + lg * 4) * 4096 + h * 128 + li;
#pragma unroll
    for (int r = 0; r < 4; r++)
#pragma unroll
      for (int n = 0; n < 8; n++)
        op[(size_t)r * 4096 + n * 16] = f2bf(oa[m][n][r] * inv[r]);
  }
}

extern "C" void kernel_launch(void* const* d_in, const int* in_sizes, int n_in,
                              void* d_out, int out_size, void* d_ws, size_t ws_size,
                              hipStream_t stream) {
  (void)in_sizes; (void)n_in; (void)out_size; (void)ws_size;
  const float* hs = (const float*)d_in[0];
  const float* wq = (const float*)d_in[1];
  const float* wk = (const float*)d_in[2];
  const float* wv = (const float*)d_in[3];
  const float* wo = (const float*)d_in[4];

  u16* ws   = (u16*)d_ws;
  u16* hs_b = ws;               // [4096][4096]
  u16* wqT  = hs_b + 16777216;  // [4096][4096]
  u16* wkT  = wqT + 16777216;   // [1024][4096]
  u16* wvT  = wkT + 4194304;    // [1024][4096]
  u16* woT  = wvT + 4194304;    // [4096][4096]
  u16* Qb   = woT + 16777216;   // [4096][4096]
  u16* Kb   = Qb + 16777216;    // [4096][1024]
  u16* VTb  = Kb + 4194304;     // [2][8][128][2048]
  u16* attnb = VTb + 4194304;   // [4096][4096]

  cast_bf16_kern<<<8192, 256, 0, stream>>>(hs, hs_b, 16777216);
  transpose_cast_kern<<<16384, 256, 0, stream>>>(wq, wqT, 4096, 4096);
  transpose_cast_kern<<<4096, 256, 0, stream>>>(wk, wkT, 4096, 1024);
  transpose_cast_kern<<<4096, 256, 0, stream>>>(wv, wvT, 4096, 1024);
  transpose_cast_kern<<<16384, 256, 0, stream>>>(wo, woT, 4096, 4096);

  gemm_bt<0><<<1024, 256, 0, stream>>>(hs_b, wqT, Qb, 4096, 4096, 4096);
  gemm_bt<0><<<256, 256, 0, stream>>>(hs_b, wkT, Kb, 4096, 1024, 4096);
  gemm_bt<1><<<256, 256, 0, stream>>>(hs_b, wvT, VTb, 4096, 1024, 4096);

  flash_attn_kern<<<1024, 256, 0, stream>>>(Qb, Kb, VTb, attnb);

  gemm_bt<2><<<1024, 256, 0, stream>>>(attnb, woT, (float*)d_out, 4096, 4096, 4096);
}

// Round 4
// 610.317 us; speedup vs baseline: 1.7129x; 1.2141x over previous
//
#include <hip/hip_runtime.h>

typedef unsigned short u16;
typedef __attribute__((ext_vector_type(8))) short bf16x8;
typedef __attribute__((ext_vector_type(8))) unsigned short u16x8;
typedef __attribute__((ext_vector_type(4))) float f32x4;

__device__ __forceinline__ u16 f2bf(float f) {
  union { float f; unsigned u; } v; v.f = f;
  unsigned r = v.u + 0x7fffu + ((v.u >> 16) & 1u);
  return (u16)(r >> 16);
}

__device__ __forceinline__ void gload16(const u16* g, u16* l) {
  __builtin_amdgcn_global_load_lds((const __attribute__((address_space(1))) void*)g,
                                   (__attribute__((address_space(3))) void*)l, 16, 0, 0);
}

// ---------------- cast f32 -> bf16 (contiguous) ----------------
__global__ __launch_bounds__(256) void cast_bf16_kern(const float* __restrict__ in,
                                                      u16* __restrict__ out, int n) {
  int i = (blockIdx.x * 256 + threadIdx.x) * 8;
  if (i >= n) return;
  float4 a = *(const float4*)(in + i);
  float4 b = *(const float4*)(in + i + 4);
  u16x8 r;
  r[0] = f2bf(a.x); r[1] = f2bf(a.y); r[2] = f2bf(a.z); r[3] = f2bf(a.w);
  r[4] = f2bf(b.x); r[5] = f2bf(b.y); r[6] = f2bf(b.z); r[7] = f2bf(b.w);
  *(u16x8*)(out + i) = r;
}

// ---------------- transpose + cast: in[K][N] f32 -> out[N][K] bf16 ----------------
__global__ __launch_bounds__(256) void transpose_cast_kern(const float* __restrict__ in,
                                                           u16* __restrict__ out, int K, int N) {
  __shared__ float tile[32][33];
  int nbx = N >> 5;
  int n0 = (blockIdx.x % nbx) << 5;
  int k0 = (blockIdx.x / nbx) << 5;
  int tx = threadIdx.x & 31, ty = threadIdx.x >> 5;
#pragma unroll
  for (int i = 0; i < 4; i++)
    tile[ty + i * 8][tx] = in[(size_t)(k0 + ty + i * 8) * N + n0 + tx];
  __syncthreads();
#pragma unroll
  for (int i = 0; i < 4; i++)
    out[(size_t)(n0 + ty + i * 8) * K + k0 + tx] = f2bf(tile[tx][ty + i * 8]);
}

// ---------------- 128^2 GEMM (kept for K/V projections, N=1024) ----------------
template <int MODE>
__global__ __launch_bounds__(256) void gemm_bt(const u16* __restrict__ A,
                                               const u16* __restrict__ Bt,
                                               void* __restrict__ Cout,
                                               int M, int N, int K) {
  __shared__ u16 As[128 * 32];
  __shared__ u16 Bs[128 * 32];
  const int tid = threadIdx.x;
  const int lane = tid & 63, wv = tid >> 6;
  const int wr = wv >> 1, wc = wv & 1;
  const int li = lane & 15, lg = lane >> 4;
  const int nbx = N >> 7;
  const int m0 = (blockIdx.x / nbx) << 7;
  const int n0 = (blockIdx.x % nbx) << 7;

  f32x4 acc[4][4];
#pragma unroll
  for (int m = 0; m < 4; m++)
#pragma unroll
    for (int n = 0; n < 4; n++) acc[m][n] = (f32x4){0.f, 0.f, 0.f, 0.f};

  const int srow = wv * 16 + (lane >> 2);
  const int skoff = (lane & 3) * 8;
  const u16* ag0 = A + (size_t)(m0 + srow) * K + skoff;
  const u16* ag1 = A + (size_t)(m0 + srow + 64) * K + skoff;
  const u16* bg0 = Bt + (size_t)(n0 + srow) * K + skoff;
  const u16* bg1 = Bt + (size_t)(n0 + srow + 64) * K + skoff;
  u16* al = As + wv * 512;
  u16* bl = Bs + wv * 512;

  for (int kt = 0; kt < K; kt += 32) {
    __syncthreads();
    gload16(ag0 + kt, al);
    gload16(ag1 + kt, al + 2048);
    gload16(bg0 + kt, bl);
    gload16(bg1 + kt, bl + 2048);
    __syncthreads();
    bf16x8 af[4], bfr[4];
#pragma unroll
    for (int m = 0; m < 4; m++)
      af[m] = *(const bf16x8*)(As + (wr * 64 + m * 16 + li) * 32 + lg * 8);
#pragma unroll
    for (int n = 0; n < 4; n++)
      bfr[n] = *(const bf16x8*)(Bs + (wc * 64 + n * 16 + li) * 32 + lg * 8);
#pragma unroll
    for (int m = 0; m < 4; m++)
#pragma unroll
      for (int n = 0; n < 4; n++)
        acc[m][n] = __builtin_amdgcn_mfma_f32_16x16x32_bf16(af[m], bfr[n], acc[m][n], 0, 0, 0);
  }

#pragma unroll
  for (int m = 0; m < 4; m++)
#pragma unroll
    for (int n = 0; n < 4; n++)
#pragma unroll
      for (int r = 0; r < 4; r++) {
        int gm = m0 + wr * 64 + m * 16 + lg * 4 + r;
        int gn = n0 + wc * 64 + n * 16 + li;
        float val = acc[m][n][r];
        if (MODE == 0) {
          ((u16*)Cout)[(size_t)gm * N + gn] = f2bf(val);
        } else {  // V^T: [B][Hkv][D][S]
          int b = gm >> 11, s = gm & 2047, kvh = gn >> 7, d = gn & 127;
          ((u16*)Cout)[(size_t)((b * 8 + kvh) * 128 + d) * 2048 + s] = f2bf(val);
        }
      }
}

// ---------------- 256^2 8-phase GEMM (T2+T3+T4+T5), hazard-free stage stream ----------------
// 512 thr = 8 waves (2M x 4N); BK=64; LDS 128KB = 2 dbuf x (A 256x64 + B 256x64) bf16.
// Stage discipline: iter t stages tile t+2 ONLY after all reads of the aliased dbuf
// region completed: B halves after phase 1 (issued phase 2), A halves after phase 2
// (issued phase 3). K-tile boundary waits vmcnt(8) = exactly tile t+2 in flight.
#define PH_PRE()                                           \
  asm volatile("" ::: "memory");                           \
  __builtin_amdgcn_s_barrier();                            \
  asm volatile("s_waitcnt lgkmcnt(0)" ::: "memory");       \
  __builtin_amdgcn_sched_barrier(0);                       \
  __builtin_amdgcn_s_setprio(1)

#define PH_POST()                                          \
  __builtin_amdgcn_s_setprio(0);                           \
  __builtin_amdgcn_sched_barrier(0);                       \
  asm volatile("" ::: "memory");                           \
  __builtin_amdgcn_s_barrier()

template <int MODE>
__global__ __launch_bounds__(512, 2) void gemm256(const u16* __restrict__ A,
                                                  const u16* __restrict__ Bt,
                                                  void* __restrict__ Cout,
                                                  int M, int N, int K) {
  __shared__ u16 lds[65536];  // 128 KiB: A at 0, B at 32768 (u16 units)
  const int tid = threadIdx.x;
  const int lane = tid & 63, w = tid >> 6;
  const int wm = w >> 2, wn = w & 3;
  const int li = lane & 15, lg = lane >> 4;
  const int NT = K >> 6;

  const int nbx = N >> 8;
  const int nwg = gridDim.x;
  const int swz = (blockIdx.x & 7) * (nwg >> 3) + (blockIdx.x >> 3);  // XCD swizzle (nwg%8==0)
  const int m0 = (swz / nbx) << 8;
  const int n0 = (swz % nbx) << 8;

  // staging: wave w covers rows w*16..+15 of each 128-row half; per-lane global col
  // pre-swizzled (chunk ^= row&7) so linear gload_lds dest + swizzled ds_read matches.
  const int srow = w * 16 + (lane >> 3);
  const int scol = ((lane & 7) ^ (lane >> 3)) << 3;
  const u16* sA0 = A + (size_t)(m0 + srow) * K + scol;
  const u16* sA1 = A + (size_t)(m0 + 128 + srow) * K + scol;
  const u16* sB0 = Bt + (size_t)(n0 + srow) * K + scol;
  const u16* sB1 = Bt + (size_t)(n0 + 128 + srow) * K + scol;
  const size_t jK = (size_t)8 * K;
  u16* dA0 = lds + w * 1024;
  u16* dA1 = lds + 8192 + w * 1024;
  u16* dB0 = lds + 32768 + w * 1024;
  u16* dB1 = lds + 32768 + 8192 + w * 1024;

#define STG(sp, dp, t_) do {                                          \
    int db_ = (t_) & 1;                                               \
    gload16((sp) + (size_t)(t_) * 64, (dp) + db_ * 16384);            \
    gload16((sp) + (size_t)(t_) * 64 + jK, (dp) + db_ * 16384 + 512); \
  } while (0)

  // prologue: stage tiles 0 AND 1 fully (16 loads); vmcnt(8) drains tile0
  STG(sA0, dA0, 0); STG(sA1, dA1, 0); STG(sB0, dB0, 0); STG(sB1, dB1, 0);
  STG(sA0, dA0, 1); STG(sA1, dA1, 1); STG(sB0, dB0, 1); STG(sB1, dB1, 1);
  asm volatile("s_waitcnt vmcnt(8)" ::: "memory");
  asm volatile("" ::: "memory");
  __builtin_amdgcn_s_barrier();

  f32x4 acc[8][4];
#pragma unroll
  for (int m = 0; m < 8; m++)
#pragma unroll
    for (int n = 0; n < 4; n++) acc[m][n] = (f32x4){0.f, 0.f, 0.f, 0.f};

  const int xsw = (li & 7) << 3;
  const int k0o = (lg * 8) ^ xsw;
  const int k1o = (32 + lg * 8) ^ xsw;
  const u16* aBase = lds + wm * 8192;
  const u16* bBase = lds + 32768 + (wn >> 1) * 8192;
  const int brow0 = (wn & 1) * 64;

  bf16x8 a[4][2], b[4][2];

  for (int t = 0; t < NT; ++t) {
    const int db = t & 1;
    const u16* Ab = aBase + db * 16384;
    const u16* Bb = bBase + db * 16384;

    // ---- phase 0: read A[mf0-3], B[nf0-1]; MFMA quad (lo,lo) ----
#pragma unroll
    for (int mf = 0; mf < 4; mf++) {
      int r = mf * 16 + li;
      a[mf][0] = *(const bf16x8*)(Ab + r * 64 + k0o);
      a[mf][1] = *(const bf16x8*)(Ab + r * 64 + k1o);
    }
#pragma unroll
    for (int nf = 0; nf < 2; nf++) {
      int r = brow0 + nf * 16 + li;
      b[nf][0] = *(const bf16x8*)(Bb + r * 64 + k0o);
      b[nf][1] = *(const bf16x8*)(Bb + r * 64 + k1o);
    }
    PH_PRE();
#pragma unroll
    for (int mf = 0; mf < 4; mf++)
#pragma unroll
      for (int nf = 0; nf < 2; nf++) {
        acc[mf][nf] = __builtin_amdgcn_mfma_f32_16x16x32_bf16(a[mf][0], b[nf][0], acc[mf][nf], 0, 0, 0);
        acc[mf][nf] = __builtin_amdgcn_mfma_f32_16x16x32_bf16(a[mf][1], b[nf][1], acc[mf][nf], 0, 0, 0);
      }
    PH_POST();

    // ---- phase 1: read B[nf2-3]; MFMA quad (lo,hi) ----
#pragma unroll
    for (int nf = 2; nf < 4; nf++) {
      int r = brow0 + nf * 16 + li;
      b[nf][0] = *(const bf16x8*)(Bb + r * 64 + k0o);
      b[nf][1] = *(const bf16x8*)(Bb + r * 64 + k1o);
    }
    PH_PRE();
#pragma unroll
    for (int mf = 0; mf < 4; mf++)
#pragma unroll
      for (int nf = 2; nf < 4; nf++) {
        acc[mf][nf] = __builtin_amdgcn_mfma_f32_16x16x32_bf16(a[mf][0], b[nf][0], acc[mf][nf], 0, 0, 0);
        acc[mf][nf] = __builtin_amdgcn_mfma_f32_16x16x32_bf16(a[mf][1], b[nf][1], acc[mf][nf], 0, 0, 0);
      }
    PH_POST();

    // ---- phase 2: read A[mf4-7]; stage B0,B1(t+2) (B reads done after phase 1); MFMA (hi,hi) ----
#pragma unroll
    for (int mf = 0; mf < 4; mf++) {
      int r = (mf + 4) * 16 + li;
      a[mf][0] = *(const bf16x8*)(Ab + r * 64 + k0o);
      a[mf][1] = *(const bf16x8*)(Ab + r * 64 + k1o);
    }
    if (t + 2 < NT) { STG(sB0, dB0, t + 2); STG(sB1, dB1, t + 2); }
    PH_PRE();
#pragma unroll
    for (int mf = 0; mf < 4; mf++)
#pragma unroll
      for (int nf = 2; nf < 4; nf++) {
        acc[mf + 4][nf] = __builtin_amdgcn_mfma_f32_16x16x32_bf16(a[mf][0], b[nf][0], acc[mf + 4][nf], 0, 0, 0);
        acc[mf + 4][nf] = __builtin_amdgcn_mfma_f32_16x16x32_bf16(a[mf][1], b[nf][1], acc[mf + 4][nf], 0, 0, 0);
      }
    PH_POST();

    // ---- phase 3: stage A0,A1(t+2) (A reads done after phase 2); MFMA (hi,lo); boundary ----
    if (t + 2 < NT) { STG(sA0, dA0, t + 2); STG(sA1, dA1, t + 2); }
    PH_PRE();
#pragma unroll
    for (int mf = 0; mf < 4; mf++)
#pragma unroll
      for (int nf = 0; nf < 2; nf++) {
        acc[mf + 4][nf] = __builtin_amdgcn_mfma_f32_16x16x32_bf16(a[mf][0], b[nf][0], acc[mf + 4][nf], 0, 0, 0);
        acc[mf + 4][nf] = __builtin_amdgcn_mfma_f32_16x16x32_bf16(a[mf][1], b[nf][1], acc[mf + 4][nf], 0, 0, 0);
      }
    __builtin_amdgcn_s_setprio(0);
    __builtin_amdgcn_sched_barrier(0);
    if (t < NT - 2) {
      asm volatile("s_waitcnt vmcnt(8)" ::: "memory");  // tile t+1 drained; t+2 in flight
    } else {
      asm volatile("s_waitcnt vmcnt(0)" ::: "memory");
    }
    asm volatile("" ::: "memory");
    __builtin_amdgcn_s_barrier();
  }

  // ---- epilogue ----
#pragma unroll
  for (int mf = 0; mf < 8; mf++)
#pragma unroll
    for (int nf = 0; nf < 4; nf++)
#pragma unroll
      for (int r = 0; r < 4; r++) {
        int gm = m0 + wm * 128 + mf * 16 + lg * 4 + r;
        int gn = n0 + wn * 64 + nf * 16 + li;
        if (MODE == 0)
          ((u16*)Cout)[(size_t)gm * N + gn] = f2bf(acc[mf][nf][r]);
        else
          ((float*)Cout)[(size_t)gm * N + gn] = acc[mf][nf][r];
      }
#undef STG
}

// ---------------- flash attention: GQA, block=(b,kvh,qtile32), 4 waves = 4 heads ----------------
__global__ __launch_bounds__(256, 2) void flash_attn_kern(const u16* __restrict__ Qg,
                                                          const u16* __restrict__ Kg,
                                                          const u16* __restrict__ VT,
                                                          u16* __restrict__ Og) {
  const int bid = blockIdx.x;
  const int qt = 63 - (bid >> 4);
  const int gh = bid & 15;
  const int b = gh >> 3, kvh = gh & 7;
  const int tid = threadIdx.x;
  const int lane = tid & 63, w = tid >> 6;
  const int li = lane & 15, lg = lane >> 4;
  const int h = kvh * 4 + w;
  const int q0 = qt << 5;
  const int nt = (qt >> 1) + 1;

  __shared__ u16 Kbuf[2][8192];
  __shared__ u16 Vbuf[2][8192];
  __shared__ u16 Ps[4][16 * 72];

  bf16x8 qf[2][4];
  {
    const u16* qp = Qg + ((size_t)(b * 2048 + q0 + li)) * 4096 + h * 128 + lg * 8;
#pragma unroll
    for (int m = 0; m < 2; m++)
#pragma unroll
      for (int ks = 0; ks < 4; ks++)
        qf[m][ks] = *(const bf16x8*)(qp + (size_t)(m * 16) * 4096 + ks * 32);
  }

  const u16* ksrc[4];
  const u16* vsrc[4];
#pragma unroll
  for (int i = 0; i < 4; i++) {
    int c = w * 4 + i;
    int krow = c * 4 + (lane >> 4);
    int kinner = ((lane & 15) * 16) ^ ((krow & 7) << 4);
    ksrc[i] = Kg + (size_t)(b * 2048 + krow) * 1024 + kvh * 128 + (kinner >> 1);
    int vrow = c * 8 + (lane >> 3);
    int vinner = ((lane & 7) * 16) ^ ((vrow & 7) << 4);
    vsrc[i] = VT + (size_t)((b * 8 + kvh) * 128 + vrow) * 2048 + (vinner >> 1);
  }
#pragma unroll
  for (int i = 0; i < 4; i++) {
    int c = w * 4 + i;
    gload16(ksrc[i], &Kbuf[0][c * 512]);
    gload16(vsrc[i], &Vbuf[0][c * 512]);
    ksrc[i] += 64 * 1024;
    vsrc[i] += 64;
  }

  f32x4 oa[2][8];
#pragma unroll
  for (int m = 0; m < 2; m++)
#pragma unroll
    for (int n = 0; n < 8; n++) oa[m][n] = (f32x4){0.f, 0.f, 0.f, 0.f};
  f32x4 lacc[2];
  lacc[0] = (f32x4){0.f, 0.f, 0.f, 0.f};
  lacc[1] = (f32x4){0.f, 0.f, 0.f, 0.f};
  float mrun[2][4];
#pragma unroll
  for (int m = 0; m < 2; m++)
#pragma unroll
    for (int r = 0; r < 4; r++) mrun[m][r] = -1e30f;

  const float scale = 0.08838834764831845f;
  bf16x8 onesf;
#pragma unroll
  for (int j = 0; j < 8; j++) onesf[j] = (short)0x3F80;

  asm volatile("s_waitcnt vmcnt(0)\n\ts_barrier" ::: "memory");

  for (int t = 0; t < nt; ++t) {
    const int cur = t & 1;
    const u16* KB = Kbuf[cur];
    const u16* VB = Vbuf[cur];
    if (t + 1 < nt) {
#pragma unroll
      for (int i = 0; i < 4; i++) {
        int c = w * 4 + i;
        gload16(ksrc[i], &Kbuf[cur ^ 1][c * 512]);
        gload16(vsrc[i], &Vbuf[cur ^ 1][c * 512]);
        ksrc[i] += 64 * 1024;
        vsrc[i] += 64;
      }
    }

    f32x4 sacc[2][4];
#pragma unroll
    for (int m = 0; m < 2; m++)
#pragma unroll
      for (int n = 0; n < 4; n++) sacc[m][n] = (f32x4){0.f, 0.f, 0.f, 0.f};
    __builtin_amdgcn_s_setprio(1);
#pragma unroll
    for (int n = 0; n < 4; n++) {
      int krow = n * 16 + li;
      const u16* kb = KB + krow * 128;
      int sw = (krow & 7) << 4;
#pragma unroll
      for (int ks = 0; ks < 4; ks++) {
        bf16x8 kf = *(const bf16x8*)(kb + (((ks * 64 + lg * 16) ^ sw) >> 1));
        sacc[0][n] = __builtin_amdgcn_mfma_f32_16x16x32_bf16(qf[0][ks], kf, sacc[0][n], 0, 0, 0);
        sacc[1][n] = __builtin_amdgcn_mfma_f32_16x16x32_bf16(qf[1][ks], kf, sacc[1][n], 0, 0, 0);
      }
    }
    __builtin_amdgcn_s_setprio(0);

#pragma unroll
    for (int m = 0; m < 2; m++)
#pragma unroll
      for (int n = 0; n < 4; n++)
#pragma unroll
        for (int r = 0; r < 4; r++) sacc[m][n][r] *= scale;
    if (t == nt - 1) {
      const int kv0 = t * 64;
#pragma unroll
      for (int m = 0; m < 2; m++)
#pragma unroll
        for (int r = 0; r < 4; r++) {
          int q = q0 + m * 16 + lg * 4 + r;
#pragma unroll
          for (int n = 0; n < 4; n++)
            if (kv0 + n * 16 + li > q) sacc[m][n][r] = -1e30f;
        }
    }

#pragma unroll
    for (int m = 0; m < 2; m++)
#pragma unroll
      for (int r = 0; r < 4; r++) {
        float mx = fmaxf(fmaxf(sacc[m][0][r], sacc[m][1][r]), fmaxf(sacc[m][2][r], sacc[m][3][r]));
        mx = fmaxf(mx, __shfl_xor(mx, 1, 64));
        mx = fmaxf(mx, __shfl_xor(mx, 2, 64));
        mx = fmaxf(mx, __shfl_xor(mx, 4, 64));
        mx = fmaxf(mx, __shfl_xor(mx, 8, 64));
        float mnew = fmaxf(mrun[m][r], mx);
        float corr = __expf(mrun[m][r] - mnew);
        mrun[m][r] = mnew;
#pragma unroll
        for (int n = 0; n < 4; n++) sacc[m][n][r] = __expf(sacc[m][n][r] - mnew);
        lacc[m][r] *= corr;
#pragma unroll
        for (int n = 0; n < 8; n++) oa[m][n][r] *= corr;
      }

    bf16x8 pf[2][2];
    u16* Pw = Ps[w];
#pragma unroll
    for (int m = 0; m < 2; m++) {
#pragma unroll
      for (int n = 0; n < 4; n++)
#pragma unroll
        for (int r = 0; r < 4; r++)
          Pw[(lg * 4 + r) * 72 + n * 16 + li] = f2bf(sacc[m][n][r]);
      asm volatile("s_waitcnt lgkmcnt(0)" ::: "memory");
#pragma unroll
      for (int kvs = 0; kvs < 2; kvs++)
        pf[m][kvs] = *(const bf16x8*)(Pw + li * 72 + kvs * 32 + lg * 8);
      asm volatile("s_waitcnt lgkmcnt(0)" ::: "memory");
      __builtin_amdgcn_sched_barrier(0);
    }

    __builtin_amdgcn_s_setprio(1);
#pragma unroll
    for (int kvs = 0; kvs < 2; kvs++) {
#pragma unroll
      for (int n = 0; n < 8; n++) {
        int vrow = n * 16 + li;
        bf16x8 vf = *(const bf16x8*)(VB + vrow * 64 +
                                     (((kvs * 64 + lg * 16) ^ ((vrow & 7) << 4)) >> 1));
        oa[0][n] = __builtin_amdgcn_mfma_f32_16x16x32_bf16(pf[0][kvs], vf, oa[0][n], 0, 0, 0);
        oa[1][n] = __builtin_amdgcn_mfma_f32_16x16x32_bf16(pf[1][kvs], vf, oa[1][n], 0, 0, 0);
      }
      lacc[0] = __builtin_amdgcn_mfma_f32_16x16x32_bf16(pf[0][kvs], onesf, lacc[0], 0, 0, 0);
      lacc[1] = __builtin_amdgcn_mfma_f32_16x16x32_bf16(pf[1][kvs], onesf, lacc[1], 0, 0, 0);
    }
    __builtin_amdgcn_s_setprio(0);

    asm volatile("s_waitcnt vmcnt(0)\n\ts_barrier" ::: "memory");
  }

#pragma unroll
  for (int m = 0; m < 2; m++) {
    float inv[4];
#pragma unroll
    for (int r = 0; r < 4; r++) inv[r] = 1.0f / lacc[m][r];
    u16* op = Og + (size_t)(b * 2048 + q0 + m * 16 + lg * 4) * 4096 + h * 128 + li;
#pragma unroll
    for (int r = 0; r < 4; r++)
#pragma unroll
      for (int n = 0; n < 8; n++)
        op[(size_t)r * 4096 + n * 16] = f2bf(oa[m][n][r] * inv[r]);
  }
}

extern "C" void kernel_launch(void* const* d_in, const int* in_sizes, int n_in,
                              void* d_out, int out_size, void* d_ws, size_t ws_size,
                              hipStream_t stream) {
  (void)in_sizes; (void)n_in; (void)out_size; (void)ws_size;
  const float* hs = (const float*)d_in[0];
  const float* wq = (const float*)d_in[1];
  const float* wk = (const float*)d_in[2];
  const float* wv = (const float*)d_in[3];
  const float* wo = (const float*)d_in[4];

  u16* ws   = (u16*)d_ws;
  u16* hs_b = ws;               // [4096][4096]
  u16* wqT  = hs_b + 16777216;  // [4096][4096]
  u16* wkT  = wqT + 16777216;   // [1024][4096]
  u16* wvT  = wkT + 4194304;    // [1024][4096]
  u16* woT  = wvT + 4194304;    // [4096][4096]
  u16* Qb   = woT + 16777216;   // [4096][4096]
  u16* Kb   = Qb + 16777216;    // [4096][1024]
  u16* VTb  = Kb + 4194304;     // [2][8][128][2048]
  u16* attnb = VTb + 4194304;   // [4096][4096]

  cast_bf16_kern<<<8192, 256, 0, stream>>>(hs, hs_b, 16777216);
  transpose_cast_kern<<<16384, 256, 0, stream>>>(wq, wqT, 4096, 4096);
  transpose_cast_kern<<<4096, 256, 0, stream>>>(wk, wkT, 4096, 1024);
  transpose_cast_kern<<<4096, 256, 0, stream>>>(wv, wvT, 4096, 1024);
  transpose_cast_kern<<<16384, 256, 0, stream>>>(wo, woT, 4096, 4096);

  gemm256<0><<<256, 512, 0, stream>>>(hs_b, wqT, Qb, 4096, 4096, 4096);
  gemm_bt<0><<<256, 256, 0, stream>>>(hs_b, wkT, Kb, 4096, 1024, 4096);
  gemm_bt<1><<<256, 256, 0, stream>>>(hs_b, wvT, VTb, 4096, 1024, 4096);

  flash_attn_kern<<<1024, 256, 0, stream>>>(Qb, Kb, VTb, attnb);

  gemm256<2><<<256, 512, 0, stream>>>(attnb, woT, (float*)d_out, 4096, 4096, 4096);
}